// Round 4
// baseline (275.184 us; speedup 1.0000x reference)
//
#include <hip/hip_runtime.h>
#include <hip/hip_bf16.h>

typedef unsigned short u16;
typedef __attribute__((ext_vector_type(8))) short short8;
typedef __attribute__((ext_vector_type(4))) float f32x4;

constexpr int N = 8192;
constexpr int D = 1024;
constexpr float INVT = 1.0f / 0.07f;
constexpr int BK = 32;
constexpr int KT = D / BK;                     // 32 K-tiles
constexpr int NBLK = 32;                       // 8192 / 256 row-blocks
constexpr int NTRI = NBLK * (NBLK + 1) / 2;    // 528 lower-tri tiles (8 | 528)

// ---- workspace layout (bytes) ----
constexpr size_t OFF_FBF  = 0;                       // N*D bf16 = 16 MiB
constexpr size_t OFF_SUME = 16777216;                // N f32 (32 KiB)
constexpr size_t OFF_POSS = OFF_SUME + 32768;        // N f32 (32 KiB)
constexpr size_t OFF_HIST = OFF_POSS + 32768;        // 32 i32 (pad 128)
constexpr size_t OFF_TYPE = OFF_HIST + 128;          // N i32 (32 KiB)
constexpr int ZERO_WORDS = (32768 + 32768 + 128) / 4;

__global__ __launch_bounds__(256) void k_zero(float* __restrict__ p, int n) {
  int i = blockIdx.x * 256 + threadIdx.x;
  if (i < n) p[i] = 0.0f;
}

__device__ __forceinline__ u16 f2bf(float f) {
  __hip_bfloat16 h = __float2bfloat16(f);
  union { __hip_bfloat16 h; u16 u; } cv; cv.h = h; return cv.u;
}

// one wave per row: 4 rows/block, no cross-wave sync
__global__ __launch_bounds__(256) void k_norm(
    const float* __restrict__ feat, const long long* __restrict__ et,
    u16* __restrict__ fbf, int* __restrict__ types, int* __restrict__ hist) {
  const int row = blockIdx.x * 4 + (threadIdx.x >> 6);
  const int l = threadIdx.x & 63;
  const float4* src = (const float4*)(feat + (size_t)row * D);
  float4 v[4];
  float ss = 0.f;
  #pragma unroll
  for (int c = 0; c < 4; ++c) {
    v[c] = src[c * 64 + l];
    ss += v[c].x * v[c].x + v[c].y * v[c].y + v[c].z * v[c].z + v[c].w * v[c].w;
  }
  #pragma unroll
  for (int m = 32; m; m >>= 1) ss += __shfl_xor(ss, m);
  const float sc = 1.0f / fmaxf(sqrtf(ss), 1e-12f);
  ushort4* dst = (ushort4*)(fbf + (size_t)row * D);
  #pragma unroll
  for (int c = 0; c < 4; ++c) {
    ushort4 o;
    o.x = f2bf(v[c].x * sc); o.y = f2bf(v[c].y * sc);
    o.z = f2bf(v[c].z * sc); o.w = f2bf(v[c].w * sc);
    dst[c * 64 + l] = o;
  }
  if (l == 0) {
    int ty = (int)et[row];
    types[row] = ty;
    atomicAdd(&hist[ty], 1);
  }
}

__device__ __forceinline__ void async_ld16(const u16* g, u16* l) {
  __builtin_amdgcn_global_load_lds(
      (const __attribute__((address_space(1))) void*)g,
      (__attribute__((address_space(3))) void*)l, 16, 0, 0);
}

__device__ __forceinline__ void mfma16(f32x4& d, short8 a, short8 b) {
  asm volatile("v_mfma_f32_16x16x32_bf16 %0, %1, %2, %0"
               : "+v"(d) : "v"(a), "v"(b));
}

// 256x256 lower-tri tiles of sim = fbf*fbf^T/T.
// Counted-vmcnt deep pipeline: BK=32, 4-deep LDS ring (128 KiB), staging
// runs 3 K-tiles ahead; wait = vmcnt(8) (tiles t+2,t+3 stay in flight) so
// consumed loads are ~2 iterations (~1000cy) old. 2 phases x 16 MFMA per
// K-tile, setprio around clusters (T5). LDS image is slot-major
// ((slot,row) -> slot*256+row, via per-lane GLOBAL src; LDS dest linear
// per global_load_lds rules) -> each 16-lane ds_read_b128 group hits 256
// contiguous bytes = minimal 2-way bank aliasing.
__global__ __launch_bounds__(512, 2) void k_gemm(
    const u16* __restrict__ fbf, const int* __restrict__ types,
    float* __restrict__ sum_exp, float* __restrict__ pos_sum) {
  __shared__ u16 As[4][256 * 32];   // 64 KiB
  __shared__ u16 Bs[4][256 * 32];   // 64 KiB
  __shared__ int rt[256], ct[256];

  const int pid = blockIdx.x;
  const int x = (pid & 7) * (NTRI / 8) + (pid >> 3);   // bijective XCD swizzle
  int rb = (int)((sqrtf(8.0f * (float)x + 1.0f) - 1.0f) * 0.5f);
  while ((rb + 1) * (rb + 2) / 2 <= x) ++rb;
  while (rb * (rb + 1) / 2 > x) --rb;
  const int cb = x - rb * (rb + 1) / 2;
  const int brow = rb * 256, bcol = cb * 256;
  const bool diag = (rb == cb);

  const int tid = threadIdx.x;
  const int lane = tid & 63;
  const int wid = tid >> 6;
  const int wr = wid >> 2;   // 0..1 (M)
  const int wc = wid & 3;    // 0..3 (N)

  if (tid < 256) rt[tid] = types[brow + tid];
  else           ct[tid - 256] = types[bcol + tid - 256];

  f32x4 acc[8][4];
  #pragma unroll
  for (int i = 0; i < 8; ++i)
    #pragma unroll
    for (int j = 0; j < 4; ++j) acc[i][j] = (f32x4){0.f, 0.f, 0.f, 0.f};

  // ---- staging: per K-tile per matrix = 256 rows x 32 cols = 16 KiB
  //   = 2 instr/thread. Thread t, instr j writes LDS elem (j*512+t)*8,
  //   i.e. slot-major cell (slot = j*2 + t>>8, row = t&255).
  const int srow = tid & 255;
  const int shi  = tid >> 8;                       // 0/1 (wave-uniform)
  const u16* gA = fbf + (size_t)(brow + srow) * D; // + t*BK + slot*8
  const u16* gB = fbf + (size_t)(bcol + srow) * D;
  const int ldsu = (wid * 64) * 8;                 // wave-uniform dest base

  #define ISSUE_A(tt) { u16* dA = (u16*)As[(tt) & 3] + ldsu;          \
    async_ld16(gA + (tt) * BK + shi * 8,       dA);                   \
    async_ld16(gA + (tt) * BK + (2 + shi) * 8, dA + 4096); }
  #define ISSUE_B(tt) { u16* dB = (u16*)Bs[(tt) & 3] + ldsu;          \
    async_ld16(gB + (tt) * BK + shi * 8,       dB);                   \
    async_ld16(gB + (tt) * BK + (2 + shi) * 8, dB + 4096); }

  // ---- fragment reads: lane's 16B = (slot = lane>>4, row) -> elem
  //   (slot*256 + row)*8; 16-lane groups read 256B contiguous.
  const int slotR = lane >> 4;
  const int arow = wr * 128 + (lane & 15);         // + mi*16
  const int brw  = wc * 64 + (lane & 15);          // + ni*16
  #define AOFF(mi) ((slotR * 256 + arow + (mi) * 16) * 8)
  #define BOFF(ni) ((slotR * 256 + brw  + (ni) * 16) * 8)

  // prologue: stage tiles 0,1,2; ensure tile 0 landed (8 youngest in flight)
  ISSUE_A(0) ISSUE_B(0) ISSUE_A(1) ISSUE_B(1) ISSUE_A(2) ISSUE_B(2)
  asm volatile("s_waitcnt vmcnt(8)" ::: "memory");
  __syncthreads();

  #define BAR() __builtin_amdgcn_s_barrier()

  for (int t = 0; t < KT; ++t) {
    const u16* Ac = As[t & 3];
    const u16* Bc = Bs[t & 3];
    const bool more = (t + 3 < KT);
    short8 a[4], b[4];

    // ---- phase 0: issue A(t+3); frags a0-3,b0-3; MFMA mi 0-3
    if (more) ISSUE_A(t + 3)
    #pragma unroll
    for (int q = 0; q < 4; ++q) {
      a[q] = *(const short8*)(Ac + AOFF(q));
      b[q] = *(const short8*)(Bc + BOFF(q));
    }
    BAR();
    __builtin_amdgcn_s_setprio(1);
    #pragma unroll
    for (int mi = 0; mi < 4; ++mi)
      #pragma unroll
      for (int ni = 0; ni < 4; ++ni) mfma16(acc[mi][ni], a[mi], b[ni]);
    __builtin_amdgcn_s_setprio(0);
    BAR();

    // ---- phase 1: issue B(t+3); frags a4-7; MFMA mi 4-7; counted wait
    if (more) ISSUE_B(t + 3)
    #pragma unroll
    for (int q = 0; q < 4; ++q) a[q] = *(const short8*)(Ac + AOFF(4 + q));
    BAR();
    __builtin_amdgcn_s_setprio(1);
    #pragma unroll
    for (int mi = 0; mi < 4; ++mi)
      #pragma unroll
      for (int ni = 0; ni < 4; ++ni) mfma16(acc[4 + mi][ni], a[mi], b[ni]);
    __builtin_amdgcn_s_setprio(0);
    // tiles t+2,t+3 (8 loads) may stay in flight; t+1 must have landed
    if (t < KT - 3)       asm volatile("s_waitcnt vmcnt(8)" ::: "memory");
    else if (t == KT - 3) asm volatile("s_waitcnt vmcnt(4)" ::: "memory");
    else                  asm volatile("s_waitcnt vmcnt(0)" ::: "memory");
    BAR();
  }

  // MFMA -> VALU read hazard guard (inline-asm MFMA opaque to hazard recog.)
  asm volatile("s_nop 7\n\ts_nop 7\n\ts_nop 7");
  #pragma unroll
  for (int i = 0; i < 8; ++i)
    #pragma unroll
    for (int j = 0; j < 4; ++j) asm volatile("" : "+v"(acc[i][j]));

  // epilogue: C/D layout col = lane&15, row = (lane>>4)*4 + reg  [m89]
  const int csub = lane & 15;
  const int rsub = (lane >> 4) * 4;
  int gcolv[4], ctv[4];
  #pragma unroll
  for (int ni = 0; ni < 4; ++ni) {
    const int cl = wc * 64 + ni * 16 + csub;
    gcolv[ni] = bcol + cl;
    ctv[ni] = ct[cl];
  }
  float cse[4] = {0.f, 0.f, 0.f, 0.f};
  float cps[4] = {0.f, 0.f, 0.f, 0.f};

  #pragma unroll
  for (int mi = 0; mi < 8; ++mi) {
    #pragma unroll
    for (int r = 0; r < 4; ++r) {
      const int rl = wr * 128 + mi * 16 + rsub + r;
      const int grow = brow + rl;
      const int rty = rt[rl];
      float se = 0.f, ps = 0.f;
      #pragma unroll
      for (int ni = 0; ni < 4; ++ni) {
        const float s = acc[mi][ni][r] * INVT;
        const float e = __expf(s);
        const bool match = (ctv[ni] == rty);
        if (diag) {
          if (gcolv[ni] != grow) { se += e; if (match) ps += s; }
        } else {
          se += e; if (match) ps += s;
          cse[ni] += e; if (match) cps[ni] += s;   // transpose -> row gcolv[ni]
        }
      }
      #pragma unroll
      for (int m = 8; m; m >>= 1) {
        se += __shfl_xor(se, m);
        ps += __shfl_xor(ps, m);
      }
      if (csub == 0) {
        atomicAdd(&sum_exp[grow], se);
        atomicAdd(&pos_sum[grow], ps);
      }
    }
  }

  if (!diag) {
    #pragma unroll
    for (int ni = 0; ni < 4; ++ni) {
      float se = cse[ni], ps = cps[ni];
      se += __shfl_xor(se, 16); se += __shfl_xor(se, 32);
      ps += __shfl_xor(ps, 16); ps += __shfl_xor(ps, 32);
      if (lane < 16) {
        atomicAdd(&sum_exp[gcolv[ni]], se);
        atomicAdd(&pos_sum[gcolv[ni]], ps);
      }
    }
  }
}

__global__ __launch_bounds__(1024) void k_final(
    const float* __restrict__ sum_exp, const float* __restrict__ pos_sum,
    const int* __restrict__ types, const int* __restrict__ hist,
    float* __restrict__ out) {
  const int t = threadIdx.x;
  float ls = 0.f, cnt = 0.f;
  for (int r = t; r < N; r += 1024) {
    const int pc = hist[types[r]] - 1;
    if (pc > 0) {
      const float pm = pos_sum[r] / (float)pc;
      ls += -logf(__expf(pm) / sum_exp[r] + 1e-10f);
      cnt += 1.f;
    }
  }
  #pragma unroll
  for (int m = 32; m; m >>= 1) {
    ls += __shfl_xor(ls, m);
    cnt += __shfl_xor(cnt, m);
  }
  __shared__ float s1[16], s2[16];
  if ((t & 63) == 0) { s1[t >> 6] = ls; s2[t >> 6] = cnt; }
  __syncthreads();
  if (t == 0) {
    float T = 0.f, C = 0.f;
    for (int i = 0; i < 16; ++i) { T += s1[i]; C += s2[i]; }
    out[0] = (C > 0.f) ? T / C : 0.f;
  }
}

extern "C" void kernel_launch(void* const* d_in, const int* in_sizes, int n_in,
                              void* d_out, int out_size, void* d_ws, size_t ws_size,
                              hipStream_t stream) {
  const float* feat = (const float*)d_in[0];
  const long long* et = (const long long*)d_in[1];
  char* ws = (char*)d_ws;
  u16* fbf      = (u16*)(ws + OFF_FBF);
  float* sum_e  = (float*)(ws + OFF_SUME);
  float* pos_s  = (float*)(ws + OFF_POSS);
  int* hist     = (int*)(ws + OFF_HIST);
  int* types    = (int*)(ws + OFF_TYPE);
  float* out    = (float*)d_out;

  k_zero<<<(ZERO_WORDS + 255) / 256, 256, 0, stream>>>(sum_e, ZERO_WORDS);
  k_norm<<<N / 4, 256, 0, stream>>>(feat, et, fbf, types, hist);
  k_gemm<<<NTRI, 512, 0, stream>>>(fbf, types, sum_e, pos_s);
  k_final<<<1, 1024, 0, stream>>>(sum_e, pos_s, types, hist, out);
}

// Round 5
// 198.835 us; speedup vs baseline: 1.3840x; 1.3840x over previous
//
#include <hip/hip_runtime.h>
#include <hip/hip_bf16.h>

typedef unsigned short u16;
typedef __attribute__((ext_vector_type(4))) int   i32x4;
typedef __attribute__((ext_vector_type(4))) float f32x4;

constexpr int N = 8192;
constexpr int D = 1024;
constexpr float INVT = 1.0f / 0.07f;
constexpr int BK = 64;                         // i8 k per tile
constexpr int KT = D / BK;                     // 16 K-tiles
constexpr int NBLK = 64;                       // 8192 / 128 row-blocks
constexpr int NTRI = NBLK * (NBLK + 1) / 2;    // 2080 lower-tri tiles (8|2080)

// ---- workspace layout (bytes) ----
constexpr size_t OFF_Q8    = 0;                      // N*D i8 = 8 MiB
constexpr size_t OFF_SUME  = 8388608;                // N f32 (32 KiB)
constexpr size_t OFF_POSS  = OFF_SUME + 32768;       // N f32
constexpr size_t OFF_HIST  = OFF_POSS + 32768;       // 32 i32 (pad 128)
constexpr size_t OFF_TYPE  = OFF_HIST + 128;         // N i32
constexpr size_t OFF_SCALE = OFF_TYPE + 32768;       // N f32
constexpr int ZERO_WORDS = (32768 + 32768 + 128) / 4;  // sume+poss+hist

__global__ __launch_bounds__(256) void k_zero(float* __restrict__ p, int n) {
  int i = blockIdx.x * 256 + threadIdx.x;
  if (i < n) p[i] = 0.0f;
}

// one wave per row: normalize, per-row absmax, quantize to i8, scale out
__global__ __launch_bounds__(256) void k_norm(
    const float* __restrict__ feat, const long long* __restrict__ et,
    signed char* __restrict__ q8, float* __restrict__ scales,
    int* __restrict__ types, int* __restrict__ hist) {
  const int row = blockIdx.x * 4 + (threadIdx.x >> 6);
  const int l = threadIdx.x & 63;
  const float4* src = (const float4*)(feat + (size_t)row * D);
  float4 v[4];
  float ss = 0.f, ma = 0.f;
  #pragma unroll
  for (int c = 0; c < 4; ++c) {
    v[c] = src[c * 64 + l];
    ss += v[c].x * v[c].x + v[c].y * v[c].y + v[c].z * v[c].z + v[c].w * v[c].w;
    ma = fmaxf(ma, fmaxf(fmaxf(fabsf(v[c].x), fabsf(v[c].y)),
                         fmaxf(fabsf(v[c].z), fabsf(v[c].w))));
  }
  #pragma unroll
  for (int m = 32; m; m >>= 1) {
    ss += __shfl_xor(ss, m);
    ma = fmaxf(ma, __shfl_xor(ma, m));
  }
  const float sc = 1.0f / fmaxf(sqrtf(ss), 1e-12f);
  const float man = ma * sc;                       // normalized row absmax
  const float invq = 127.0f / fmaxf(man, 1e-30f);  // f_norm -> i8
  const float qf = sc * invq;
  int* dst = (int*)(q8 + (size_t)row * D);
  #pragma unroll
  for (int c = 0; c < 4; ++c) {
    const int b0 = (unsigned char)(signed char)__float2int_rn(v[c].x * qf);
    const int b1 = (unsigned char)(signed char)__float2int_rn(v[c].y * qf);
    const int b2 = (unsigned char)(signed char)__float2int_rn(v[c].z * qf);
    const int b3 = (unsigned char)(signed char)__float2int_rn(v[c].w * qf);
    dst[c * 64 + l] = b0 | (b1 << 8) | (b2 << 16) | (b3 << 24);
  }
  if (l == 0) {
    scales[row] = man / 127.0f;                    // sim = acc*s_i*s_j
    int ty = (int)et[row];
    types[row] = ty;
    atomicAdd(&hist[ty], 1);
  }
}

__device__ __forceinline__ void async_ld16(const signed char* g,
                                           signed char* l) {
  __builtin_amdgcn_global_load_lds(
      (const __attribute__((address_space(1))) void*)g,
      (__attribute__((address_space(3))) void*)l, 16, 0, 0);
}

__device__ __forceinline__ void mfma_i8(i32x4& d, i32x4 a, i32x4 b) {
  asm volatile("v_mfma_i32_16x16x64_i8 %0, %1, %2, %0"
               : "+v"(d) : "v"(a), "v"(b));
}

// 128x128 lower-tri tiles of sim = (q8 . q8^T) * s_i * s_j / T.
// r2's proven 2-barrier structure (4 waves 2x2, 64x64/wave, ~3 blk/CU),
// upgraded to i8 BK=64 (half staging bytes, half barriers, 2x MFMA rate).
// LDS image slot-major: byte (slot*128+row)*16 holds q8[row][k=slot*16+j]
// (via per-lane GLOBAL src col; gload_lds dest stays linear) -> each
// 16-lane ds_read_b128 group hits 256 contiguous bytes = no bank conflict.
// A and B staged identically, so any internal k-permutation of the i8
// MFMA cancels between operands; only the 16x16 row/col map matters.
__global__ __launch_bounds__(256) void k_gemm(
    const signed char* __restrict__ q8, const float* __restrict__ scales,
    const int* __restrict__ types,
    float* __restrict__ sum_exp, float* __restrict__ pos_sum) {
  __shared__ signed char As[128 * 64];   // 8 KiB
  __shared__ signed char Bs[128 * 64];   // 8 KiB
  __shared__ int rt[128], ct[128];
  __shared__ float rsl[128], csl[128];

  const int pid = blockIdx.x;
  const int x = (pid & 7) * (NTRI / 8) + (pid >> 3);   // bijective XCD swizzle
  int rb = (int)((sqrtf(8.0f * (float)x + 1.0f) - 1.0f) * 0.5f);
  while ((rb + 1) * (rb + 2) / 2 <= x) ++rb;
  while (rb * (rb + 1) / 2 > x) --rb;
  const int cb = x - rb * (rb + 1) / 2;
  const int brow = rb * 128, bcol = cb * 128;
  const bool diag = (rb == cb);

  const int tid = threadIdx.x;
  const int lane = tid & 63;
  const int wid = tid >> 6;
  const int wr = wid >> 1, wc = wid & 1;

  if (tid < 128) {
    rt[tid] = types[brow + tid];
    rsl[tid] = scales[brow + tid] * INVT;   // fold 1/T into row scale
  } else {
    ct[tid - 128] = types[bcol + tid - 128];
    csl[tid - 128] = scales[bcol + tid - 128];
  }

  i32x4 acc[4][4];
  #pragma unroll
  for (int i = 0; i < 4; ++i)
    #pragma unroll
    for (int j = 0; j < 4; ++j) acc[i][j] = (i32x4){0, 0, 0, 0};

  // staging: 2 issues per matrix per K-tile; issue j: thread t -> LDS byte
  // j*4096 + t*16 = (slot,row) with slot = 2j + (t>>7), row = t&127.
  const int row_s = tid & 127;
  const int slot_s = tid >> 7;                     // 0/1
  const signed char* gA = q8 + (size_t)(brow + row_s) * D + slot_s * 16;
  const signed char* gB = q8 + (size_t)(bcol + row_s) * D + slot_s * 16;
  signed char* lA = As + (tid & ~63) * 16;         // wave-uniform dest
  signed char* lB = Bs + (tid & ~63) * 16;

  // fragment reads: lane's 16B = k-slot (lane>>4), row (16-lane groups
  // read 256B contiguous)
  const int slotR = lane >> 4;
  const int arow = wr * 64 + (lane & 15);          // + mi*16
  const int brw  = wc * 64 + (lane & 15);          // + ni*16
  #define AOFF(mi) ((slotR * 128 + arow + (mi) * 16) * 16)
  #define BOFF(ni) ((slotR * 128 + brw  + (ni) * 16) * 16)

  for (int kt = 0; kt < KT; ++kt) {
    const int ko = kt * BK;
    async_ld16(gA + ko,      lA);
    async_ld16(gA + ko + 32, lA + 4096);
    async_ld16(gB + ko,      lB);
    async_ld16(gB + ko + 32, lB + 4096);
    __syncthreads();   // compiler drains vmcnt before s_barrier
    i32x4 a[4], b[4];
    #pragma unroll
    for (int q = 0; q < 4; ++q) {
      a[q] = *(const i32x4*)(As + AOFF(q));
      b[q] = *(const i32x4*)(Bs + BOFF(q));
    }
    #pragma unroll
    for (int mi = 0; mi < 4; ++mi)
      #pragma unroll
      for (int ni = 0; ni < 4; ++ni) mfma_i8(acc[mi][ni], a[mi], b[ni]);
    __syncthreads();
  }

  // MFMA -> VALU read hazard guard (inline-asm MFMA opaque to hazard recog.)
  asm volatile("s_nop 7\n\ts_nop 7\n\ts_nop 7");
  #pragma unroll
  for (int i = 0; i < 4; ++i)
    #pragma unroll
    for (int j = 0; j < 4; ++j) asm volatile("" : "+v"(acc[i][j]));

  // epilogue: C/D layout col = lane&15, row = (lane>>4)*4 + reg  [m89]
  const int csub = lane & 15;
  const int rsub = (lane >> 4) * 4;
  int gcolv[4], ctv[4];
  float cfv[4];
  #pragma unroll
  for (int ni = 0; ni < 4; ++ni) {
    const int cl = wc * 64 + ni * 16 + csub;
    gcolv[ni] = bcol + cl;
    ctv[ni] = ct[cl];
    cfv[ni] = csl[cl];
  }
  float cse[4] = {0.f, 0.f, 0.f, 0.f};
  float cps[4] = {0.f, 0.f, 0.f, 0.f};

  #pragma unroll
  for (int mi = 0; mi < 4; ++mi) {
    #pragma unroll
    for (int r = 0; r < 4; ++r) {
      const int rl = wr * 64 + mi * 16 + rsub + r;
      const int grow = brow + rl;
      const int rty = rt[rl];
      const float rfac = rsl[rl];                 // includes 1/T
      float se = 0.f, ps = 0.f;
      #pragma unroll
      for (int ni = 0; ni < 4; ++ni) {
        const float s = (float)acc[mi][ni][r] * rfac * cfv[ni];
        const float e = __expf(s);
        const bool match = (ctv[ni] == rty);
        if (diag) {
          if (gcolv[ni] != grow) { se += e; if (match) ps += s; }
        } else {
          se += e; if (match) ps += s;
          cse[ni] += e; if (match) cps[ni] += s;  // transpose -> row gcolv[ni]
        }
      }
      #pragma unroll
      for (int m = 8; m; m >>= 1) {
        se += __shfl_xor(se, m);
        ps += __shfl_xor(ps, m);
      }
      if (csub == 0) {
        atomicAdd(&sum_exp[grow], se);
        atomicAdd(&pos_sum[grow], ps);
      }
    }
  }

  if (!diag) {
    #pragma unroll
    for (int ni = 0; ni < 4; ++ni) {
      float se = cse[ni], ps = cps[ni];
      se += __shfl_xor(se, 16); se += __shfl_xor(se, 32);
      ps += __shfl_xor(ps, 16); ps += __shfl_xor(ps, 32);
      if (lane < 16) {
        atomicAdd(&sum_exp[gcolv[ni]], se);
        atomicAdd(&pos_sum[gcolv[ni]], ps);
      }
    }
  }
}

__global__ __launch_bounds__(1024) void k_final(
    const float* __restrict__ sum_exp, const float* __restrict__ pos_sum,
    const int* __restrict__ types, const int* __restrict__ hist,
    float* __restrict__ out) {
  const int t = threadIdx.x;
  float ls = 0.f, cnt = 0.f;
  for (int r = t; r < N; r += 1024) {
    const int pc = hist[types[r]] - 1;
    if (pc > 0) {
      const float pm = pos_sum[r] / (float)pc;
      ls += -logf(__expf(pm) / sum_exp[r] + 1e-10f);
      cnt += 1.f;
    }
  }
  #pragma unroll
  for (int m = 32; m; m >>= 1) {
    ls += __shfl_xor(ls, m);
    cnt += __shfl_xor(cnt, m);
  }
  __shared__ float s1[16], s2[16];
  if ((t & 63) == 0) { s1[t >> 6] = ls; s2[t >> 6] = cnt; }
  __syncthreads();
  if (t == 0) {
    float T = 0.f, C = 0.f;
    for (int i = 0; i < 16; ++i) { T += s1[i]; C += s2[i]; }
    out[0] = (C > 0.f) ? T / C : 0.f;
  }
}

extern "C" void kernel_launch(void* const* d_in, const int* in_sizes, int n_in,
                              void* d_out, int out_size, void* d_ws, size_t ws_size,
                              hipStream_t stream) {
  const float* feat = (const float*)d_in[0];
  const long long* et = (const long long*)d_in[1];
  char* ws = (char*)d_ws;
  signed char* q8 = (signed char*)(ws + OFF_Q8);
  float* sum_e  = (float*)(ws + OFF_SUME);
  float* pos_s  = (float*)(ws + OFF_POSS);
  int* hist     = (int*)(ws + OFF_HIST);
  int* types    = (int*)(ws + OFF_TYPE);
  float* scale  = (float*)(ws + OFF_SCALE);
  float* out    = (float*)d_out;

  k_zero<<<(ZERO_WORDS + 255) / 256, 256, 0, stream>>>(sum_e, ZERO_WORDS);
  k_norm<<<N / 4, 256, 0, stream>>>(feat, et, q8, scale, types, hist);
  k_gemm<<<NTRI, 256, 0, stream>>>(q8, scale, types, sum_e, pos_s);
  k_final<<<1, 1024, 0, stream>>>(sum_e, pos_s, types, hist, out);
}

// Round 6
// 146.602 us; speedup vs baseline: 1.8771x; 1.3563x over previous
//
#include <hip/hip_runtime.h>
#include <hip/hip_bf16.h>

typedef unsigned short u16;
typedef __attribute__((ext_vector_type(4))) int   i32x4;
typedef __attribute__((ext_vector_type(4))) float f32x4;

constexpr int N = 8192;
constexpr int D = 1024;
constexpr float INVT = 1.0f / 0.07f;
constexpr int BK = 64;                         // i8 k per tile
constexpr int KT = D / BK;                     // 16 K-tiles
constexpr int NBLK = 64;                       // 8192 / 128 row-blocks
constexpr int NTRI = NBLK * (NBLK + 1) / 2;    // 2080 lower-tri tiles (8|2080)

// ---- workspace layout (bytes) ----
constexpr size_t OFF_Q8    = 0;                      // N*D i8 = 8 MiB
constexpr size_t OFF_SUME  = 8388608;                // N f32 (32 KiB)
constexpr size_t OFF_POSS  = OFF_SUME + 32768;       // N f32
constexpr size_t OFF_TYPE  = OFF_POSS + 32768;       // N i32
constexpr size_t OFF_SCALE = OFF_TYPE + 32768;       // N f32

// one wave per row: normalize, per-row absmax, quantize to i8, scale out.
// Also zeroes sum_exp/pos_sum (4 words per block) -- replaces k_zero.
__global__ __launch_bounds__(256) void k_norm(
    const float* __restrict__ feat, const long long* __restrict__ et,
    signed char* __restrict__ q8, float* __restrict__ scales,
    int* __restrict__ types,
    float* __restrict__ sum_exp, float* __restrict__ pos_sum) {
  if (threadIdx.x < 4)
    sum_exp[blockIdx.x * 4 + threadIdx.x] = 0.f;
  else if (threadIdx.x < 8)
    pos_sum[blockIdx.x * 4 + threadIdx.x - 4] = 0.f;

  const int row = blockIdx.x * 4 + (threadIdx.x >> 6);
  const int l = threadIdx.x & 63;
  const float4* src = (const float4*)(feat + (size_t)row * D);
  float4 v[4];
  float ss = 0.f, ma = 0.f;
  #pragma unroll
  for (int c = 0; c < 4; ++c) {
    v[c] = src[c * 64 + l];
    ss += v[c].x * v[c].x + v[c].y * v[c].y + v[c].z * v[c].z + v[c].w * v[c].w;
    ma = fmaxf(ma, fmaxf(fmaxf(fabsf(v[c].x), fabsf(v[c].y)),
                         fmaxf(fabsf(v[c].z), fabsf(v[c].w))));
  }
  #pragma unroll
  for (int m = 32; m; m >>= 1) {
    ss += __shfl_xor(ss, m);
    ma = fmaxf(ma, __shfl_xor(ma, m));
  }
  const float sc = 1.0f / fmaxf(sqrtf(ss), 1e-12f);
  const float man = ma * sc;                       // normalized row absmax
  const float invq = 127.0f / fmaxf(man, 1e-30f);  // f_norm -> i8
  const float qf = sc * invq;
  int* dst = (int*)(q8 + (size_t)row * D);
  #pragma unroll
  for (int c = 0; c < 4; ++c) {
    const int b0 = (unsigned char)(signed char)__float2int_rn(v[c].x * qf);
    const int b1 = (unsigned char)(signed char)__float2int_rn(v[c].y * qf);
    const int b2 = (unsigned char)(signed char)__float2int_rn(v[c].z * qf);
    const int b3 = (unsigned char)(signed char)__float2int_rn(v[c].w * qf);
    dst[c * 64 + l] = b0 | (b1 << 8) | (b2 << 16) | (b3 << 24);
  }
  if (l == 0) {
    scales[row] = man / 127.0f;                    // sim = acc*s_i*s_j
    types[row] = (int)et[row];
  }
}

__device__ __forceinline__ void async_ld16(const signed char* g,
                                           signed char* l) {
  __builtin_amdgcn_global_load_lds(
      (const __attribute__((address_space(1))) void*)g,
      (__attribute__((address_space(3))) void*)l, 16, 0, 0);
}

__device__ __forceinline__ void mfma_i8(i32x4& d, i32x4 a, i32x4 b) {
  asm volatile("v_mfma_i32_16x16x64_i8 %0, %1, %2, %0"
               : "+v"(d) : "v"(a), "v"(b));
}

// 128x128 lower-tri tiles of sim = (q8 . q8^T) * s_i * s_j / T.
// r5 skeleton (4 waves 2x2, 64x64/wave, i8 BK=64, slot-major LDS) with the
// minimal T3/T4 pipeline: 3-deep LDS ring (48 KiB -> 3 blk/CU kept), stage
// tile t+2 at iter t, counted s_waitcnt vmcnt(4) (tile t+1 must land; the
// 4 youngest loads stay in flight across the barrier), ONE s_barrier per
// K-step. Buffer safety: tile t+2 overwrites buf[(t+2)%3], last read at
// iter t-1; those reads completed (operand lgkm waits before MFMA) before
// the end-of-(t-1) barrier, and the new loads are issued after it.
__global__ __launch_bounds__(256) void k_gemm(
    const signed char* __restrict__ q8, const float* __restrict__ scales,
    const int* __restrict__ types,
    float* __restrict__ sum_exp, float* __restrict__ pos_sum) {
  __shared__ signed char As[3][128 * 64];   // 24 KiB
  __shared__ signed char Bs[3][128 * 64];   // 24 KiB
  __shared__ int rt[128], ct[128];
  __shared__ float rsl[128], csl[128];

  const int pid = blockIdx.x;
  const int x = (pid & 7) * (NTRI / 8) + (pid >> 3);   // bijective XCD swizzle
  int rb = (int)((sqrtf(8.0f * (float)x + 1.0f) - 1.0f) * 0.5f);
  while ((rb + 1) * (rb + 2) / 2 <= x) ++rb;
  while (rb * (rb + 1) / 2 > x) --rb;
  const int cb = x - rb * (rb + 1) / 2;
  const int brow = rb * 128, bcol = cb * 128;
  const bool diag = (rb == cb);

  const int tid = threadIdx.x;
  const int lane = tid & 63;
  const int wid = tid >> 6;
  const int wr = wid >> 1, wc = wid & 1;

  if (tid < 128) {
    rt[tid] = types[brow + tid];
    rsl[tid] = scales[brow + tid] * INVT;   // fold 1/T into row scale
  } else {
    ct[tid - 128] = types[bcol + tid - 128];
    csl[tid - 128] = scales[bcol + tid - 128];
  }

  i32x4 acc[4][4];
  #pragma unroll
  for (int i = 0; i < 4; ++i)
    #pragma unroll
    for (int j = 0; j < 4; ++j) acc[i][j] = (i32x4){0, 0, 0, 0};

  // staging: per matrix per K-tile = 128 rows x 64 k = 8 KiB = 2 instr.
  // issue j: thread t -> LDS byte j*4096 + t*16 = slot-major (slot =
  // 2j + (t>>7), row = t&127); realized via per-lane GLOBAL col, LDS
  // dest linear (global_load_lds: wave-uniform base + lane*16).
  const int row_s = tid & 127;
  const int slot_s = tid >> 7;                     // 0/1
  const signed char* gA = q8 + (size_t)(brow + row_s) * D + slot_s * 16;
  const signed char* gB = q8 + (size_t)(bcol + row_s) * D + slot_s * 16;
  const int ldsu = (tid & ~63) * 16;               // wave-uniform dest base

  #define ISSUE(tt) {                                                 \
    signed char* dA = (signed char*)As[(tt) % 3] + ldsu;              \
    signed char* dB = (signed char*)Bs[(tt) % 3] + ldsu;              \
    const int ko = (tt) * BK;                                         \
    async_ld16(gA + ko,      dA);                                     \
    async_ld16(gA + ko + 32, dA + 4096);                              \
    async_ld16(gB + ko,      dB);                                     \
    async_ld16(gB + ko + 32, dB + 4096); }

  // fragment reads: lane's 16B = k-slot (lane>>4); 16-lane groups read
  // 256B contiguous -> conflict-free.
  const int slotR = lane >> 4;
  const int arow = wr * 64 + (lane & 15);          // + mi*16
  const int brw  = wc * 64 + (lane & 15);          // + ni*16
  #define AOFF(mi) ((slotR * 128 + arow + (mi) * 16) * 16)
  #define BOFF(ni) ((slotR * 128 + brw  + (ni) * 16) * 16)

  // prologue: stage tiles 0,1; wait tile 0 (4 youngest in flight);
  // lgkmcnt(0) publishes rt/ct/rsl/csl ds_writes before the barrier.
  ISSUE(0)
  ISSUE(1)
  asm volatile("s_waitcnt vmcnt(4) lgkmcnt(0)" ::: "memory");
  __builtin_amdgcn_s_barrier();

  for (int t = 0; t < KT; ++t) {
    if (t + 2 < KT) ISSUE(t + 2)
    const signed char* Ac = As[t % 3];
    const signed char* Bc = Bs[t % 3];
    i32x4 a[4], b[4];
    #pragma unroll
    for (int q = 0; q < 4; ++q) {
      a[q] = *(const i32x4*)(Ac + AOFF(q));
      b[q] = *(const i32x4*)(Bc + BOFF(q));
    }
    #pragma unroll
    for (int mi = 0; mi < 4; ++mi)
      #pragma unroll
      for (int ni = 0; ni < 4; ++ni) mfma_i8(acc[mi][ni], a[mi], b[ni]);
    // tile t+1 must have landed; tile t+2's 4 loads stay in flight.
    if (t + 2 < KT) asm volatile("s_waitcnt vmcnt(4)" ::: "memory");
    else            asm volatile("s_waitcnt vmcnt(0)" ::: "memory");
    __builtin_amdgcn_s_barrier();
  }

  // MFMA -> VALU read hazard guard (inline-asm MFMA opaque to hazard recog.)
  asm volatile("s_nop 7\n\ts_nop 7\n\ts_nop 7");
  #pragma unroll
  for (int i = 0; i < 4; ++i)
    #pragma unroll
    for (int j = 0; j < 4; ++j) asm volatile("" : "+v"(acc[i][j]));

  // epilogue: C/D layout col = lane&15, row = (lane>>4)*4 + reg  [m89]
  const int csub = lane & 15;
  const int rsub = (lane >> 4) * 4;
  int gcolv[4], ctv[4];
  float cfv[4];
  #pragma unroll
  for (int ni = 0; ni < 4; ++ni) {
    const int cl = wc * 64 + ni * 16 + csub;
    gcolv[ni] = bcol + cl;
    ctv[ni] = ct[cl];
    cfv[ni] = csl[cl];
  }
  float cse[4] = {0.f, 0.f, 0.f, 0.f};
  float cps[4] = {0.f, 0.f, 0.f, 0.f};

  #pragma unroll
  for (int mi = 0; mi < 4; ++mi) {
    #pragma unroll
    for (int r = 0; r < 4; ++r) {
      const int rl = wr * 64 + mi * 16 + rsub + r;
      const int grow = brow + rl;
      const int rty = rt[rl];
      const float rfac = rsl[rl];                 // includes 1/T
      float se = 0.f, ps = 0.f;
      #pragma unroll
      for (int ni = 0; ni < 4; ++ni) {
        const float s = (float)acc[mi][ni][r] * rfac * cfv[ni];
        const float e = __expf(s);
        const bool match = (ctv[ni] == rty);
        if (diag) {
          if (gcolv[ni] != grow) { se += e; if (match) ps += s; }
        } else {
          se += e; if (match) ps += s;
          cse[ni] += e; if (match) cps[ni] += s;  // transpose -> row gcolv[ni]
        }
      }
      #pragma unroll
      for (int m = 8; m; m >>= 1) {
        se += __shfl_xor(se, m);
        ps += __shfl_xor(ps, m);
      }
      if (csub == 0) {
        atomicAdd(&sum_exp[grow], se);
        atomicAdd(&pos_sum[grow], ps);
      }
    }
  }

  if (!diag) {
    #pragma unroll
    for (int ni = 0; ni < 4; ++ni) {
      float se = cse[ni], ps = cps[ni];
      se += __shfl_xor(se, 16); se += __shfl_xor(se, 32);
      ps += __shfl_xor(ps, 16); ps += __shfl_xor(ps, 32);
      if (lane < 16) {
        atomicAdd(&sum_exp[gcolv[ni]], se);
        atomicAdd(&pos_sum[gcolv[ni]], ps);
      }
    }
  }
}

__global__ __launch_bounds__(1024) void k_final(
    const float* __restrict__ sum_exp, const float* __restrict__ pos_sum,
    const int* __restrict__ types, float* __restrict__ out) {
  const int t = threadIdx.x;
  __shared__ int h[32];
  if (t < 32) h[t] = 0;
  __syncthreads();
  int ty[8];
  #pragma unroll
  for (int i = 0; i < 8; ++i) {
    ty[i] = types[t + i * 1024];
    atomicAdd(&h[ty[i]], 1);
  }
  __syncthreads();
  float ls = 0.f, cnt = 0.f;
  #pragma unroll
  for (int i = 0; i < 8; ++i) {
    const int r = t + i * 1024;
    const int pc = h[ty[i]] - 1;
    if (pc > 0) {
      const float pm = pos_sum[r] / (float)pc;
      ls += -logf(__expf(pm) / sum_exp[r] + 1e-10f);
      cnt += 1.f;
    }
  }
  #pragma unroll
  for (int m = 32; m; m >>= 1) {
    ls += __shfl_xor(ls, m);
    cnt += __shfl_xor(cnt, m);
  }
  __shared__ float s1[16], s2[16];
  if ((t & 63) == 0) { s1[t >> 6] = ls; s2[t >> 6] = cnt; }
  __syncthreads();
  if (t == 0) {
    float T = 0.f, C = 0.f;
    for (int i = 0; i < 16; ++i) { T += s1[i]; C += s2[i]; }
    out[0] = (C > 0.f) ? T / C : 0.f;
  }
}

extern "C" void kernel_launch(void* const* d_in, const int* in_sizes, int n_in,
                              void* d_out, int out_size, void* d_ws, size_t ws_size,
                              hipStream_t stream) {
  const float* feat = (const float*)d_in[0];
  const long long* et = (const long long*)d_in[1];
  char* ws = (char*)d_ws;
  signed char* q8 = (signed char*)(ws + OFF_Q8);
  float* sum_e  = (float*)(ws + OFF_SUME);
  float* pos_s  = (float*)(ws + OFF_POSS);
  int* types    = (int*)(ws + OFF_TYPE);
  float* scale  = (float*)(ws + OFF_SCALE);
  float* out    = (float*)d_out;

  k_norm<<<N / 4, 256, 0, stream>>>(feat, et, q8, scale, types, sum_e, pos_s);
  k_gemm<<<NTRI, 256, 0, stream>>>(q8, scale, types, sum_e, pos_s);
  k_final<<<1, 1024, 0, stream>>>(sum_e, pos_s, types, out);
}

// Round 7
// 143.964 us; speedup vs baseline: 1.9115x; 1.0183x over previous
//
#include <hip/hip_runtime.h>
#include <hip/hip_bf16.h>

typedef unsigned short u16;
typedef __attribute__((ext_vector_type(4))) int   i32x4;
typedef __attribute__((ext_vector_type(4))) float f32x4;

constexpr int N = 8192;
constexpr int D = 1024;
constexpr float INVT = 1.0f / 0.07f;
constexpr int BK = 64;                         // i8 k per tile
constexpr int KT = D / BK;                     // 16 K-tiles
constexpr int NBLK = 64;                       // 8192 / 128 row-blocks
constexpr int NTRI = NBLK * (NBLK + 1) / 2;    // 2080 lower-tri tiles

// ---- workspace layout (bytes) ----
constexpr size_t OFF_Q8    = 0;                      // N*D i8 = 8 MiB
constexpr size_t OFF_SUME  = 8388608;                // N f32 (32 KiB)
constexpr size_t OFF_POSS  = OFF_SUME + 32768;       // N f32
constexpr size_t OFF_TYPE  = OFF_POSS + 32768;       // N i32
constexpr size_t OFF_SCALE = OFF_TYPE + 32768;       // N f32

// one wave per row: normalize, per-row absmax, quantize to i8, scale out.
// Also zeroes sum_exp/pos_sum (4 words per block) -- replaces k_zero.
__global__ __launch_bounds__(256) void k_norm(
    const float* __restrict__ feat, const long long* __restrict__ et,
    signed char* __restrict__ q8, float* __restrict__ scales,
    int* __restrict__ types,
    float* __restrict__ sum_exp, float* __restrict__ pos_sum) {
  if (threadIdx.x < 4)
    sum_exp[blockIdx.x * 4 + threadIdx.x] = 0.f;
  else if (threadIdx.x < 8)
    pos_sum[blockIdx.x * 4 + threadIdx.x - 4] = 0.f;

  const int row = blockIdx.x * 4 + (threadIdx.x >> 6);
  const int l = threadIdx.x & 63;
  const float4* src = (const float4*)(feat + (size_t)row * D);
  float4 v[4];
  float ss = 0.f, ma = 0.f;
  #pragma unroll
  for (int c = 0; c < 4; ++c) {
    v[c] = src[c * 64 + l];
    ss += v[c].x * v[c].x + v[c].y * v[c].y + v[c].z * v[c].z + v[c].w * v[c].w;
    ma = fmaxf(ma, fmaxf(fmaxf(fabsf(v[c].x), fabsf(v[c].y)),
                         fmaxf(fabsf(v[c].z), fabsf(v[c].w))));
  }
  #pragma unroll
  for (int m = 32; m; m >>= 1) {
    ss += __shfl_xor(ss, m);
    ma = fmaxf(ma, __shfl_xor(ma, m));
  }
  const float sc = 1.0f / fmaxf(sqrtf(ss), 1e-12f);
  const float man = ma * sc;                       // normalized row absmax
  const float invq = 127.0f / fmaxf(man, 1e-30f);  // f_norm -> i8
  const float qf = sc * invq;
  int* dst = (int*)(q8 + (size_t)row * D);
  #pragma unroll
  for (int c = 0; c < 4; ++c) {
    const int b0 = (unsigned char)(signed char)__float2int_rn(v[c].x * qf);
    const int b1 = (unsigned char)(signed char)__float2int_rn(v[c].y * qf);
    const int b2 = (unsigned char)(signed char)__float2int_rn(v[c].z * qf);
    const int b3 = (unsigned char)(signed char)__float2int_rn(v[c].w * qf);
    dst[c * 64 + l] = b0 | (b1 << 8) | (b2 << 16) | (b3 << 24);
  }
  if (l == 0) {
    scales[row] = man / 127.0f;                    // sim = acc*s_i*s_j
    types[row] = (int)et[row];
  }
}

__device__ __forceinline__ void async_ld16(const signed char* g,
                                           signed char* l) {
  __builtin_amdgcn_global_load_lds(
      (const __attribute__((address_space(1))) void*)g,
      (__attribute__((address_space(3))) void*)l, 16, 0, 0);
}

__device__ __forceinline__ void mfma_i8(i32x4& d, i32x4 a, i32x4 b) {
  asm volatile("v_mfma_i32_16x16x64_i8 %0, %1, %2, %0"
               : "+v"(d) : "v"(a), "v"(b));
}

// 128x128 lower-tri tiles of sim = (q8 . q8^T) * s_i * s_j / T.
// r5's proven inner structure (4 waves 2x2, single-buffer, 2 barriers/step,
// i8 BK=64, slot-major LDS, 18 KiB).
// NEW: L2-locality XCD mapping. q8 (8 MB) exceeds the 4 MiB per-XCD L2, so
// the old contiguous tri-band mapping thrashed (XCD7's concurrent blocks
// held ~12 MB of B-panels -> every K-step fetched from L3 at queued
// multi-us latency). Now XCD x owns columns cbs[j] = 8j + (j odd ? 7-x : x)
// (exactly 260 tiles each; pair counts sum to 65), enumerated rb-outer /
// cb-inner: 8 B-panels (1 MB) stay L2-hot, A-panels stream with 8x reuse.
// Working set ~2.5 MB < 4 MB L2.
__global__ __launch_bounds__(256) void k_gemm(
    const signed char* __restrict__ q8, const float* __restrict__ scales,
    const int* __restrict__ types,
    float* __restrict__ sum_exp, float* __restrict__ pos_sum) {
  __shared__ signed char As[128 * 64];   // 8 KiB
  __shared__ signed char Bs[128 * 64];   // 8 KiB
  __shared__ int rt[128], ct[128];
  __shared__ float rsl[128], csl[128];

  // ---- tile decode: XCD x (= pid%8, HW round-robin), local index l ----
  const int pid = blockIdx.x;
  const int x = pid & 7;
  const int l = pid >> 3;                       // 0..259
  int cbs[8];
  #pragma unroll
  for (int j = 0; j < 8; ++j) cbs[j] = 8 * j + ((j & 1) ? 7 - x : x);
  // T(r) = #tiles of this XCD in rows < r = sum_j max(0, r - cbs[j]);
  // binary search largest rb with T(rb) <= l.
  int lo = 0, hi = 63;
  while (lo < hi) {
    const int mid = (lo + hi + 1) >> 1;
    int T = 0;
    #pragma unroll
    for (int j = 0; j < 8; ++j) T += max(0, mid - cbs[j]);
    if (T <= l) lo = mid; else hi = mid - 1;
  }
  const int rb = lo;
  int Tr = 0;
  #pragma unroll
  for (int j = 0; j < 8; ++j) Tr += max(0, rb - cbs[j]);
  const int rem = l - Tr;                       // 0..7: index into cb prefix
  int cb = 0;
  #pragma unroll
  for (int j = 0; j < 8; ++j) if (j == rem) cb = cbs[j];

  const int brow = rb * 128, bcol = cb * 128;
  const bool diag = (rb == cb);

  const int tid = threadIdx.x;
  const int lane = tid & 63;
  const int wid = tid >> 6;
  const int wr = wid >> 1, wc = wid & 1;

  if (tid < 128) {
    rt[tid] = types[brow + tid];
    rsl[tid] = scales[brow + tid] * INVT;   // fold 1/T into row scale
  } else {
    ct[tid - 128] = types[bcol + tid - 128];
    csl[tid - 128] = scales[bcol + tid - 128];
  }

  i32x4 acc[4][4];
  #pragma unroll
  for (int i = 0; i < 4; ++i)
    #pragma unroll
    for (int j = 0; j < 4; ++j) acc[i][j] = (i32x4){0, 0, 0, 0};

  // staging: per matrix per K-tile = 128 rows x 64 k = 8 KiB = 2 instr.
  // issue j: thread t -> LDS byte j*4096 + t*16 = slot-major (slot =
  // 2j + (t>>7), row = t&127); realized via per-lane GLOBAL col, LDS
  // dest linear (global_load_lds: wave-uniform base + lane*16).
  const int row_s = tid & 127;
  const int slot_s = tid >> 7;                     // 0/1
  const signed char* gA = q8 + (size_t)(brow + row_s) * D + slot_s * 16;
  const signed char* gB = q8 + (size_t)(bcol + row_s) * D + slot_s * 16;
  signed char* lA = As + (tid & ~63) * 16;         // wave-uniform dest
  signed char* lB = Bs + (tid & ~63) * 16;

  // fragment reads: lane's 16B = k-slot (lane>>4); 16-lane groups read
  // 256B contiguous -> conflict-free.
  const int slotR = lane >> 4;
  const int arow = wr * 64 + (lane & 15);          // + mi*16
  const int brw  = wc * 64 + (lane & 15);          // + ni*16
  #define AOFF(mi) ((slotR * 128 + arow + (mi) * 16) * 16)
  #define BOFF(ni) ((slotR * 128 + brw  + (ni) * 16) * 16)

  for (int kt = 0; kt < KT; ++kt) {
    const int ko = kt * BK;
    async_ld16(gA + ko,      lA);
    async_ld16(gA + ko + 32, lA + 4096);
    async_ld16(gB + ko,      lB);
    async_ld16(gB + ko + 32, lB + 4096);
    __syncthreads();   // compiler drains vmcnt before s_barrier
    i32x4 a[4], b[4];
    #pragma unroll
    for (int q = 0; q < 4; ++q) {
      a[q] = *(const i32x4*)(As + AOFF(q));
      b[q] = *(const i32x4*)(Bs + BOFF(q));
    }
    #pragma unroll
    for (int mi = 0; mi < 4; ++mi)
      #pragma unroll
      for (int ni = 0; ni < 4; ++ni) mfma_i8(acc[mi][ni], a[mi], b[ni]);
    __syncthreads();
  }

  // MFMA -> VALU read hazard guard (inline-asm MFMA opaque to hazard recog.)
  asm volatile("s_nop 7\n\ts_nop 7\n\ts_nop 7");
  #pragma unroll
  for (int i = 0; i < 4; ++i)
    #pragma unroll
    for (int j = 0; j < 4; ++j) asm volatile("" : "+v"(acc[i][j]));

  // epilogue: C/D layout col = lane&15, row = (lane>>4)*4 + reg  [m89]
  const int csub = lane & 15;
  const int rsub = (lane >> 4) * 4;
  int gcolv[4], ctv[4];
  float cfv[4];
  #pragma unroll
  for (int ni = 0; ni < 4; ++ni) {
    const int cl = wc * 64 + ni * 16 + csub;
    gcolv[ni] = bcol + cl;
    ctv[ni] = ct[cl];
    cfv[ni] = csl[cl];
  }
  float cse[4] = {0.f, 0.f, 0.f, 0.f};
  float cps[4] = {0.f, 0.f, 0.f, 0.f};

  #pragma unroll
  for (int mi = 0; mi < 4; ++mi) {
    #pragma unroll
    for (int r = 0; r < 4; ++r) {
      const int rl = wr * 64 + mi * 16 + rsub + r;
      const int grow = brow + rl;
      const int rty = rt[rl];
      const float rfac = rsl[rl];                 // includes 1/T
      float se = 0.f, ps = 0.f;
      #pragma unroll
      for (int ni = 0; ni < 4; ++ni) {
        const float s = (float)acc[mi][ni][r] * rfac * cfv[ni];
        const float e = __expf(s);
        const bool match = (ctv[ni] == rty);
        if (diag) {
          if (gcolv[ni] != grow) { se += e; if (match) ps += s; }
        } else {
          se += e; if (match) ps += s;
          cse[ni] += e; if (match) cps[ni] += s;  // transpose -> row gcolv[ni]
        }
      }
      #pragma unroll
      for (int m = 8; m; m >>= 1) {
        se += __shfl_xor(se, m);
        ps += __shfl_xor(ps, m);
      }
      if (csub == 0) {
        atomicAdd(&sum_exp[grow], se);
        atomicAdd(&pos_sum[grow], ps);
      }
    }
  }

  if (!diag) {
    #pragma unroll
    for (int ni = 0; ni < 4; ++ni) {
      float se = cse[ni], ps = cps[ni];
      se += __shfl_xor(se, 16); se += __shfl_xor(se, 32);
      ps += __shfl_xor(ps, 16); ps += __shfl_xor(ps, 32);
      if (lane < 16) {
        atomicAdd(&sum_exp[gcolv[ni]], se);
        atomicAdd(&pos_sum[gcolv[ni]], ps);
      }
    }
  }
}

__global__ __launch_bounds__(1024) void k_final(
    const float* __restrict__ sum_exp, const float* __restrict__ pos_sum,
    const int* __restrict__ types, float* __restrict__ out) {
  const int t = threadIdx.x;
  __shared__ int h[32];
  if (t < 32) h[t] = 0;
  __syncthreads();
  int ty[8];
  #pragma unroll
  for (int i = 0; i < 8; ++i) {
    ty[i] = types[t + i * 1024];
    atomicAdd(&h[ty[i]], 1);
  }
  __syncthreads();
  float ls = 0.f, cnt = 0.f;
  #pragma unroll
  for (int i = 0; i < 8; ++i) {
    const int r = t + i * 1024;
    const int pc = h[ty[i]] - 1;
    if (pc > 0) {
      const float pm = pos_sum[r] / (float)pc;
      ls += -logf(__expf(pm) / sum_exp[r] + 1e-10f);
      cnt += 1.f;
    }
  }
  #pragma unroll
  for (int m = 32; m; m >>= 1) {
    ls += __shfl_xor(ls, m);
    cnt += __shfl_xor(cnt, m);
  }
  __shared__ float s1[16], s2[16];
  if ((t & 63) == 0) { s1[t >> 6] = ls; s2[t >> 6] = cnt; }
  __syncthreads();
  if (t == 0) {
    float T = 0.f, C = 0.f;
    for (int i = 0; i < 16; ++i) { T += s1[i]; C += s2[i]; }
    out[0] = (C > 0.f) ? T / C : 0.f;
  }
}

extern "C" void kernel_launch(void* const* d_in, const int* in_sizes, int n_in,
                              void* d_out, int out_size, void* d_ws, size_t ws_size,
                              hipStream_t stream) {
  const float* feat = (const float*)d_in[0];
  const long long* et = (const long long*)d_in[1];
  char* ws = (char*)d_ws;
  signed char* q8 = (signed char*)(ws + OFF_Q8);
  float* sum_e  = (float*)(ws + OFF_SUME);
  float* pos_s  = (float*)(ws + OFF_POSS);
  int* types    = (int*)(ws + OFF_TYPE);
  float* scale  = (float*)(ws + OFF_SCALE);
  float* out    = (float*)d_out;

  k_norm<<<N / 4, 256, 0, stream>>>(feat, et, q8, scale, types, sum_e, pos_s);
  k_gemm<<<NTRI, 256, 0, stream>>>(q8, scale, types, sum_e, pos_s);
  k_final<<<1, 1024, 0, stream>>>(sum_e, pos_s, types, out);
}

// Round 8
// 111.883 us; speedup vs baseline: 2.4596x; 1.2867x over previous
//
#include <hip/hip_runtime.h>
#include <hip/hip_bf16.h>

typedef unsigned short u16;
typedef __attribute__((ext_vector_type(4))) int   i32x4;
typedef __attribute__((ext_vector_type(4))) float f32x4;

constexpr int N = 8192;
constexpr int D = 1024;
constexpr float INVT = 1.0f / 0.07f;
constexpr int BK = 64;                         // i8 k per tile
constexpr int KT = D / BK;                     // 16 K-tiles
constexpr int NBLK = 64;                       // 8192 / 128 row-blocks
constexpr int NTRI = NBLK * (NBLK + 1) / 2;    // 2080 lower-tri tiles
constexpr int PANEL_BYTES = 128 * 1024;        // 128 rows x 1024 i8 = 131072

// ---- workspace layout (bytes) ----
// q8 is stored TILED: panel p (128 rows), slot s (16 i8 of k), row r:
//   byte = p*131072 + s*2048 + r*16  -> one K-tile (4 slots) = 8KB contiguous
constexpr size_t OFF_Q8    = 0;                      // N*D i8 = 8 MiB (tiled)
constexpr size_t OFF_SUME  = 8388608;                // N f32 (32 KiB)
constexpr size_t OFF_POSS  = OFF_SUME + 32768;       // N f32
constexpr size_t OFF_TYPE  = OFF_POSS + 32768;       // N i32
constexpr size_t OFF_SCALE = OFF_TYPE + 32768;       // N f32

// one wave per row: normalize, per-row absmax, quantize to i8 into the
// TILED q8 layout. Also zeroes sum_exp/pos_sum (replaces k_zero).
__global__ __launch_bounds__(256) void k_norm(
    const float* __restrict__ feat, const long long* __restrict__ et,
    signed char* __restrict__ q8, float* __restrict__ scales,
    int* __restrict__ types,
    float* __restrict__ sum_exp, float* __restrict__ pos_sum) {
  if (threadIdx.x < 4)
    sum_exp[blockIdx.x * 4 + threadIdx.x] = 0.f;
  else if (threadIdx.x < 8)
    pos_sum[blockIdx.x * 4 + threadIdx.x - 4] = 0.f;

  const int row = blockIdx.x * 4 + (threadIdx.x >> 6);
  const int l = threadIdx.x & 63;
  const float4* src = (const float4*)(feat + (size_t)row * D);
  float4 v[4];
  float ss = 0.f, ma = 0.f;
  #pragma unroll
  for (int c = 0; c < 4; ++c) {
    v[c] = src[c * 64 + l];
    ss += v[c].x * v[c].x + v[c].y * v[c].y + v[c].z * v[c].z + v[c].w * v[c].w;
    ma = fmaxf(ma, fmaxf(fmaxf(fabsf(v[c].x), fabsf(v[c].y)),
                         fmaxf(fabsf(v[c].z), fabsf(v[c].w))));
  }
  #pragma unroll
  for (int m = 32; m; m >>= 1) {
    ss += __shfl_xor(ss, m);
    ma = fmaxf(ma, __shfl_xor(ma, m));
  }
  const float sc = 1.0f / fmaxf(sqrtf(ss), 1e-12f);
  const float man = ma * sc;                       // normalized row absmax
  const float invq = 127.0f / fmaxf(man, 1e-30f);  // f_norm -> i8
  const float qf = sc * invq;
  // tiled write: word w = c*64+l (k-ints) -> slot s = w>>2, byte (w&3)*4.
  // 4 lanes share a 16B slot unit; the block's 4 rows merge to full lines.
  signed char* pb = q8 + (size_t)(row >> 7) * PANEL_BYTES + (row & 127) * 16;
  #pragma unroll
  for (int c = 0; c < 4; ++c) {
    const int b0 = (unsigned char)(signed char)__float2int_rn(v[c].x * qf);
    const int b1 = (unsigned char)(signed char)__float2int_rn(v[c].y * qf);
    const int b2 = (unsigned char)(signed char)__float2int_rn(v[c].z * qf);
    const int b3 = (unsigned char)(signed char)__float2int_rn(v[c].w * qf);
    const int w = c * 64 + l;
    *(int*)(pb + (w >> 2) * 2048 + (w & 3) * 4) =
        b0 | (b1 << 8) | (b2 << 16) | (b3 << 24);
  }
  if (l == 0) {
    scales[row] = man / 127.0f;                    // sim = acc*s_i*s_j
    types[row] = (int)et[row];
  }
}

__device__ __forceinline__ void async_ld16(const signed char* g,
                                           signed char* l) {
  __builtin_amdgcn_global_load_lds(
      (const __attribute__((address_space(1))) void*)g,
      (__attribute__((address_space(3))) void*)l, 16, 0, 0);
}

__device__ __forceinline__ void mfma_i8(i32x4& d, i32x4 a, i32x4 b) {
  asm volatile("v_mfma_i32_16x16x64_i8 %0, %1, %2, %0"
               : "+v"(d) : "v"(a), "v"(b));
}

// 128x128 lower-tri tiles of sim = (q8 . q8^T) * s_i * s_j / T.
// r7 structure unchanged (4 waves 2x2, single-buffer, 2 barriers/step,
// i8 BK=64, slot-major LDS, XCD-local column ownership).
// NEW: q8 is PRE-TILED in global memory, so each K-step's staging is two
// fully-linear 4KB gload_lds sweeps per matrix (1KB contiguous per
// wave-instr, 16 fully-used lines) instead of the previous 64-line
// scatter -- 4x fewer L1/TCP line transactions, which r7's counters
// identified as the serialized resource (MfmaUtil 10%, both pipes idle,
// FETCH already minimal).
__global__ __launch_bounds__(256) void k_gemm(
    const signed char* __restrict__ q8, const float* __restrict__ scales,
    const int* __restrict__ types,
    float* __restrict__ sum_exp, float* __restrict__ pos_sum) {
  __shared__ signed char As[128 * 64];   // 8 KiB
  __shared__ signed char Bs[128 * 64];   // 8 KiB
  __shared__ int rt[128], ct[128];
  __shared__ float rsl[128], csl[128];

  // ---- tile decode: XCD x (= pid%8, HW round-robin), local index l ----
  const int pid = blockIdx.x;
  const int x = pid & 7;
  const int l = pid >> 3;                       // 0..259
  int cbs[8];
  #pragma unroll
  for (int j = 0; j < 8; ++j) cbs[j] = 8 * j + ((j & 1) ? 7 - x : x);
  // T(r) = #tiles of this XCD in rows < r = sum_j max(0, r - cbs[j]);
  // binary search largest rb with T(rb) <= l.
  int lo = 0, hi = 63;
  while (lo < hi) {
    const int mid = (lo + hi + 1) >> 1;
    int T = 0;
    #pragma unroll
    for (int j = 0; j < 8; ++j) T += max(0, mid - cbs[j]);
    if (T <= l) lo = mid; else hi = mid - 1;
  }
  const int rb = lo;
  int Tr = 0;
  #pragma unroll
  for (int j = 0; j < 8; ++j) Tr += max(0, rb - cbs[j]);
  const int rem = l - Tr;                       // 0..7: index into cb prefix
  int cb = 0;
  #pragma unroll
  for (int j = 0; j < 8; ++j) if (j == rem) cb = cbs[j];

  const int brow = rb * 128, bcol = cb * 128;
  const bool diag = (rb == cb);

  const int tid = threadIdx.x;
  const int lane = tid & 63;
  const int wid = tid >> 6;
  const int wr = wid >> 1, wc = wid & 1;

  if (tid < 128) {
    rt[tid] = types[brow + tid];
    rsl[tid] = scales[brow + tid] * INVT;   // fold 1/T into row scale
  } else {
    ct[tid - 128] = types[bcol + tid - 128];
    csl[tid - 128] = scales[bcol + tid - 128];
  }

  i32x4 acc[4][4];
  #pragma unroll
  for (int i = 0; i < 4; ++i)
    #pragma unroll
    for (int j = 0; j < 4; ++j) acc[i][j] = (i32x4){0, 0, 0, 0};

  // staging: K-tile kt of panel p = 8KB contiguous at p*131072 + kt*8192.
  // Two linear 4KB sweeps per matrix; LDS dest = tid*16 (lane*16 added by
  // HW to the wave-uniform base). LDS image = slot-major (s_loc*128+r)*16.
  const signed char* gA = q8 + (size_t)rb * PANEL_BYTES + tid * 16;
  const signed char* gB = q8 + (size_t)cb * PANEL_BYTES + tid * 16;
  signed char* lA = As + (tid & ~63) * 16;         // wave-uniform dest base
  signed char* lB = Bs + (tid & ~63) * 16;

  // fragment reads: lane's 16B = k-slot (lane>>4); 16-lane groups read
  // 256B contiguous -> conflict-free.
  const int slotR = lane >> 4;
  const int arow = wr * 64 + (lane & 15);          // + mi*16
  const int brw  = wc * 64 + (lane & 15);          // + ni*16
  #define AOFF(mi) ((slotR * 128 + arow + (mi) * 16) * 16)
  #define BOFF(ni) ((slotR * 128 + brw  + (ni) * 16) * 16)

  for (int kt = 0; kt < KT; ++kt) {
    const int ko = kt * 8192;
    async_ld16(gA + ko,        lA);
    async_ld16(gA + ko + 4096, lA + 4096);
    async_ld16(gB + ko,        lB);
    async_ld16(gB + ko + 4096, lB + 4096);
    __syncthreads();   // compiler drains vmcnt before s_barrier
    i32x4 a[4], b[4];
    #pragma unroll
    for (int q = 0; q < 4; ++q) {
      a[q] = *(const i32x4*)(As + AOFF(q));
      b[q] = *(const i32x4*)(Bs + BOFF(q));
    }
    #pragma unroll
    for (int mi = 0; mi < 4; ++mi)
      #pragma unroll
      for (int ni = 0; ni < 4; ++ni) mfma_i8(acc[mi][ni], a[mi], b[ni]);
    __syncthreads();
  }

  // MFMA -> VALU read hazard guard (inline-asm MFMA opaque to hazard recog.)
  asm volatile("s_nop 7\n\ts_nop 7\n\ts_nop 7");
  #pragma unroll
  for (int i = 0; i < 4; ++i)
    #pragma unroll
    for (int j = 0; j < 4; ++j) asm volatile("" : "+v"(acc[i][j]));

  // epilogue: C/D layout col = lane&15, row = (lane>>4)*4 + reg  [m89]
  const int csub = lane & 15;
  const int rsub = (lane >> 4) * 4;
  int gcolv[4], ctv[4];
  float cfv[4];
  #pragma unroll
  for (int ni = 0; ni < 4; ++ni) {
    const int cl = wc * 64 + ni * 16 + csub;
    gcolv[ni] = bcol + cl;
    ctv[ni] = ct[cl];
    cfv[ni] = csl[cl];
  }
  float cse[4] = {0.f, 0.f, 0.f, 0.f};
  float cps[4] = {0.f, 0.f, 0.f, 0.f};

  #pragma unroll
  for (int mi = 0; mi < 4; ++mi) {
    #pragma unroll
    for (int r = 0; r < 4; ++r) {
      const int rl = wr * 64 + mi * 16 + rsub + r;
      const int grow = brow + rl;
      const int rty = rt[rl];
      const float rfac = rsl[rl];                 // includes 1/T
      float se = 0.f, ps = 0.f;
      #pragma unroll
      for (int ni = 0; ni < 4; ++ni) {
        const float s = (float)acc[mi][ni][r] * rfac * cfv[ni];
        const float e = __expf(s);
        const bool match = (ctv[ni] == rty);
        if (diag) {
          if (gcolv[ni] != grow) { se += e; if (match) ps += s; }
        } else {
          se += e; if (match) ps += s;
          cse[ni] += e; if (match) cps[ni] += s;  // transpose -> row gcolv[ni]
        }
      }
      #pragma unroll
      for (int m = 8; m; m >>= 1) {
        se += __shfl_xor(se, m);
        ps += __shfl_xor(ps, m);
      }
      if (csub == 0) {
        atomicAdd(&sum_exp[grow], se);
        atomicAdd(&pos_sum[grow], ps);
      }
    }
  }

  if (!diag) {
    #pragma unroll
    for (int ni = 0; ni < 4; ++ni) {
      float se = cse[ni], ps = cps[ni];
      se += __shfl_xor(se, 16); se += __shfl_xor(se, 32);
      ps += __shfl_xor(ps, 16); ps += __shfl_xor(ps, 32);
      if (lane < 16) {
        atomicAdd(&sum_exp[gcolv[ni]], se);
        atomicAdd(&pos_sum[gcolv[ni]], ps);
      }
    }
  }
}

__global__ __launch_bounds__(1024) void k_final(
    const float* __restrict__ sum_exp, const float* __restrict__ pos_sum,
    const int* __restrict__ types, float* __restrict__ out) {
  const int t = threadIdx.x;
  __shared__ int h[32];
  if (t < 32) h[t] = 0;
  __syncthreads();
  int ty[8];
  #pragma unroll
  for (int i = 0; i < 8; ++i) {
    ty[i] = types[t + i * 1024];
    atomicAdd(&h[ty[i]], 1);
  }
  __syncthreads();
  float ls = 0.f, cnt = 0.f;
  #pragma unroll
  for (int i = 0; i < 8; ++i) {
    const int r = t + i * 1024;
    const int pc = h[ty[i]] - 1;
    if (pc > 0) {
      const float pm = pos_sum[r] / (float)pc;
      ls += -logf(__expf(pm) / sum_exp[r] + 1e-10f);
      cnt += 1.f;
    }
  }
  #pragma unroll
  for (int m = 32; m; m >>= 1) {
    ls += __shfl_xor(ls, m);
    cnt += __shfl_xor(cnt, m);
  }
  __shared__ float s1[16], s2[16];
  if ((t & 63) == 0) { s1[t >> 6] = ls; s2[t >> 6] = cnt; }
  __syncthreads();
  if (t == 0) {
    float T = 0.f, C = 0.f;
    for (int i = 0; i < 16; ++i) { T += s1[i]; C += s2[i]; }
    out[0] = (C > 0.f) ? T / C : 0.f;
  }
}

extern "C" void kernel_launch(void* const* d_in, const int* in_sizes, int n_in,
                              void* d_out, int out_size, void* d_ws, size_t ws_size,
                              hipStream_t stream) {
  const float* feat = (const float*)d_in[0];
  const long long* et = (const long long*)d_in[1];
  char* ws = (char*)d_ws;
  signed char* q8 = (signed char*)(ws + OFF_Q8);
  float* sum_e  = (float*)(ws + OFF_SUME);
  float* pos_s  = (float*)(ws + OFF_POSS);
  int* types    = (int*)(ws + OFF_TYPE);
  float* scale  = (float*)(ws + OFF_SCALE);
  float* out    = (float*)d_out;

  k_norm<<<N / 4, 256, 0, stream>>>(feat, et, q8, scale, types, sum_e, pos_s);
  k_gemm<<<NTRI, 256, 0, stream>>>(q8, scale, types, sum_e, pos_s);
  k_final<<<1, 1024, 0, stream>>>(sum_e, pos_s, types, out);
}